// Round 3
// baseline (310.340 us; speedup 1.0000x reference)
//
#include <hip/hip_runtime.h>
#include <hip/hip_bf16.h>

#define B_SZ 4
#define T_SEQ 1024
#define DM 128
#define ED_ 256
#define NS 64
#define CHUNKS 16
#define CLEN 64

// workspace layout (float elements). Total = 6,389,760 floats = 25.6 MB.
// Aliasing plan:
//   OFF_ZN region is reused for Bm/Cm after K2 is done with zn.
//   OFF_XSR region is reused for delta after K3 is done with xsr.
//   H0 aliases P (K5b reads P[idx],S[idx] BEFORE writing H0[idx], one thread per idx).
//   ycore aliases S (S dead after K5b).
#define OFF_Z      0u         /* 524288  f32  z (residual, read by K6)            */
#define OFF_ZN     524288u    /* 524288  f32  zn; later Bm @ +0, Cm @ +262144     */
#define OFF_XSR    1048576u   /* 1048576 f32  conv input; later delta             */
#define OFF_ZG     2097152u   /* 1048576 f32  gate                                */
#define OFF_XS     3145728u   /* 1048576 f32  conv+silu output                    */
#define OFF_WC     4194304u   /* 98304   f32  combined x_proj/dt weight (384x256) */
#define OFF_P      4292608u   /* 1048576 f32  chunk decay; later H0 (aliased)     */
#define OFF_S      5341184u   /* 1048576 f32  chunk local scan; later ycore       */

#define OFF_BM     (OFF_ZN)
#define OFF_CM     (OFF_ZN + 262144u)
#define OFF_DELTA  (OFF_XSR)
#define OFF_H0     (OFF_P)
#define OFF_YC     (OFF_S)

__device__ __forceinline__ float sigmoidf_(float x){ return 1.f/(1.f+__expf(-x)); }

// K1: z = z_seq + aux @ aux_W.T + aux_b ; zn = RMSNorm(z)*rms_w
__global__ __launch_bounds__(128) void k1_rms(const float* zseq, const float* aux, const float* auxW,
                                              const float* auxb, const float* rmsw, float* z, float* zn){
  int bt = blockIdx.x; int d = threadIdx.x;
  float a0 = aux[bt*3+0], a1 = aux[bt*3+1], a2 = aux[bt*3+2];
  float zv = zseq[bt*DM+d] + a0*auxW[d*3+0] + a1*auxW[d*3+1] + a2*auxW[d*3+2] + auxb[d];
  float s = zv*zv;
  #pragma unroll
  for (int off=32; off>=1; off>>=1) s += __shfl_down(s, off);
  __shared__ float ps[2];
  if ((threadIdx.x&63)==0) ps[threadIdx.x>>6] = s;
  __syncthreads();
  float r = rsqrtf((ps[0]+ps[1])*(1.f/DM) + 1e-5f);
  z[bt*DM+d]  = zv;
  zn[bt*DM+d] = zv*r*rmsw[d];
}

// K2: xz = zn @ in_proj_W.T -> xsr (cols 0..255), zg (cols 256..511). 8 rows/block.
__global__ __launch_bounds__(256) void k2_inproj(const float* zn, const float* W, float* xsr, float* zg){
  __shared__ float at[128][8];
  int bt0 = blockIdx.x*8; int tid = threadIdx.x;
  for (int i=tid; i<1024; i+=256){ int r=i>>7, k=i&127; at[k][r] = zn[(bt0+r)*DM + k]; }
  __syncthreads();
  float acc0[8], acc1[8];
  #pragma unroll
  for (int r=0;r<8;r++){ acc0[r]=0.f; acc1[r]=0.f; }
  int c0 = tid, c1 = tid+256;
  for (int k=0;k<128;k+=4){
    float4 w0v = *(const float4*)(W + c0*128 + k);
    float4 w1v = *(const float4*)(W + c1*128 + k);
    float w0[4] = {w0v.x, w0v.y, w0v.z, w0v.w};
    float w1[4] = {w1v.x, w1v.y, w1v.z, w1v.w};
    #pragma unroll
    for (int kk=0;kk<4;kk++){
      float a[8];
      *(float4*)&a[0] = *(const float4*)&at[k+kk][0];
      *(float4*)&a[4] = *(const float4*)&at[k+kk][4];
      #pragma unroll
      for (int r=0;r<8;r++){ acc0[r] = fmaf(a[r], w0[kk], acc0[r]); acc1[r] = fmaf(a[r], w1[kk], acc1[r]); }
    }
  }
  #pragma unroll
  for (int r=0;r<8;r++){
    int bt = bt0+r;
    xsr[bt*ED_ + c0] = acc0[r];
    zg [bt*ED_ + c0] = acc1[r];
  }
}

// K3: causal depthwise conv (k=4, left pad 3) + bias + SiLU
__global__ __launch_bounds__(256) void k3_conv(const float* xsr, const float* convW, const float* convb, float* xs){
  int bt = blockIdx.x; int e = threadIdx.x; int t = bt & (T_SEQ-1);
  float4 wv = *(const float4*)(convW + e*4);
  float s = convb[e];
  if (t>=3) s += xsr[(bt-3)*ED_+e]*wv.x;
  if (t>=2) s += xsr[(bt-2)*ED_+e]*wv.y;
  if (t>=1) s += xsr[(bt-1)*ED_+e]*wv.z;
  s += xsr[bt*ED_+e]*wv.w;
  xs[bt*ED_+e] = s * sigmoidf_(s);
}

// K4a: combined weight: rows 0..255 = dt_W @ x_proj_W[:8]; rows 256..383 = x_proj_W[8:136]
__global__ __launch_bounds__(256) void k4a_wc(const float* xprojW, const float* dtW, float* Wc){
  int r = blockIdx.x; int k = threadIdx.x;
  float v;
  if (r < 256){
    v = 0.f;
    #pragma unroll
    for (int j=0;j<8;j++) v += dtW[r*8+j] * xprojW[j*256+k];
  } else {
    v = xprojW[(8 + r-256)*256 + k];
  }
  Wc[r*256+k] = v;
}

// K4b: [delta_pre | B | C] = xs @ Wc.T ; delta = softplus(delta_pre + dt_b)
__global__ __launch_bounds__(384) void k4b_xproj(const float* xs, const float* Wc, const float* dtb,
                                                 float* delta, float* Bm, float* Cm){
  __shared__ float at[256][8];
  int bt0 = blockIdx.x*8; int tid = threadIdx.x;
  for (int i=tid;i<2048;i+=384){ int r=i>>8,k=i&255; at[k][r] = xs[(bt0+r)*ED_ + k]; }
  __syncthreads();
  float acc[8];
  #pragma unroll
  for (int r=0;r<8;r++) acc[r]=0.f;
  int c = tid;
  for (int k=0;k<256;k+=4){
    float4 wv = *(const float4*)(Wc + c*256 + k);
    float w[4] = {wv.x, wv.y, wv.z, wv.w};
    #pragma unroll
    for (int kk=0;kk<4;kk++){
      float a[8];
      *(float4*)&a[0] = *(const float4*)&at[k+kk][0];
      *(float4*)&a[4] = *(const float4*)&at[k+kk][4];
      #pragma unroll
      for (int r=0;r<8;r++) acc[r] = fmaf(a[r], w[kk], acc[r]);
    }
  }
  if (c < 256){
    float bc = dtb[c];
    #pragma unroll
    for (int r=0;r<8;r++){
      float x = acc[r] + bc;
      delta[(bt0+r)*ED_ + c] = (x > 20.f) ? x : log1pf(__expf(x));
    }
  } else if (c < 320){
    #pragma unroll
    for (int r=0;r<8;r++) Bm[(bt0+r)*NS + (c-256)] = acc[r];
  } else {
    #pragma unroll
    for (int r=0;r<8;r++) Cm[(bt0+r)*NS + (c-320)] = acc[r];
  }
}

// K5a: per-chunk local scan S (seed 0) and chunk decay P = exp(A * sum(delta)).
// wave g = (b, e, chunk); lane = state n.
__global__ __launch_bounds__(256) void k5a_chunk(const float* delta, const float* xs, const float* Bm,
                                                  const float* Alog, float* P, float* S){
  int g = blockIdx.x*4 + (threadIdx.x>>6);
  int n = threadIdx.x & 63;
  int c = g & 15, e = (g>>4)&255, b = g>>12;
  float A = -__expf(Alog[e*NS+n]);
  int base = b*T_SEQ + c*CLEN;
  float s = 0.f, sd = 0.f;
  for (int tt=0; tt<CLEN; ++tt){
    int bt = base+tt;
    float dlt = delta[bt*ED_+e];
    float x   = xs[bt*ED_+e];
    float bm  = Bm[bt*NS+n];
    float a = __expf(dlt*A);
    s = fmaf(a, s, dlt*x*bm);
    sd += dlt;
  }
  P[g*NS+n] = __expf(sd*A);
  S[g*NS+n] = s;
}

// K5b: chunk-prefix: H0[c] = scan of (P,S) over chunks, one thread per (b,e,n).
// NOTE: H0 aliases P — each element is read (p,s) BEFORE H0[idx] is written,
// and each idx is owned by exactly one thread. Do not add __restrict__ here.
__global__ __launch_bounds__(256) void k5b_h0(const float* P, const float* S, float* H0){
  int t = blockIdx.x*256 + threadIdx.x;
  int n = t & 63, e = (t>>6)&255, b = t>>14;
  int gb = (b*256+e)*16;
  float h = 0.f;
  for (int c=0;c<16;c++){
    int idx = (gb+c)*64 + n;
    float p = P[idx];
    float s = S[idx];
    H0[idx] = h;
    h = fmaf(p, h, s);
  }
}

// K5c: final scan seeded with H0; y = (sum_n h*C + D*x) * silu(zg). ycore aliases S (dead).
__global__ __launch_bounds__(256) void k5c_scan(const float* delta, const float* xs, const float* Bm,
                                                 const float* Cm, const float* zg, const float* Alog,
                                                 const float* Dp, const float* H0, float* ycore){
  int g = blockIdx.x*4 + (threadIdx.x>>6);
  int n = threadIdx.x & 63;
  int c = g & 15, e = (g>>4)&255, b = g>>12;
  float A = -__expf(Alog[e*NS+n]);
  float De = Dp[e];
  float h = H0[g*NS+n];
  int base = b*T_SEQ + c*CLEN;
  for (int tt=0; tt<CLEN; ++tt){
    int bt = base+tt;
    float dlt = delta[bt*ED_+e];
    float x   = xs[bt*ED_+e];
    float bm  = Bm[bt*NS+n];
    float cm  = Cm[bt*NS+n];
    float a = __expf(dlt*A);
    h = fmaf(a, h, dlt*x*bm);
    float p = h*cm;
    #pragma unroll
    for (int off=32; off>=1; off>>=1) p += __shfl_down(p, off);
    if (n==0){
      float zgv = zg[bt*ED_+e];
      float y = p + De*x;
      ycore[bt*ED_+e] = y * zgv * sigmoidf_(zgv);
    }
  }
}

// K6: out = LayerNorm(ycore @ out_proj_W.T + 2*z) * ln_w + ln_b  (f32 store)
__global__ __launch_bounds__(256) void k6_out(const float* ycore, const float* W, const float* z,
                                               const float* lnw, const float* lnb, float* out){
  __shared__ float yt[256][8];
  __shared__ float psum[4][4], psq[4][4];
  int bt0 = blockIdx.x*8; int tid = threadIdx.x;
  int d = tid & 127, gdx = tid>>7;
  for (int i=tid;i<2048;i+=256){ int r=i>>8,k=i&255; yt[k][r] = ycore[(bt0+r)*ED_ + k]; }
  __syncthreads();
  float acc[4] = {0.f,0.f,0.f,0.f};
  for (int k=0;k<256;k+=4){
    float4 wv = *(const float4*)(W + d*256 + k);
    float w[4] = {wv.x, wv.y, wv.z, wv.w};
    #pragma unroll
    for (int kk=0;kk<4;kk++){
      float4 q = *(const float4*)&yt[k+kk][gdx*4];
      acc[0] = fmaf(q.x, w[kk], acc[0]);
      acc[1] = fmaf(q.y, w[kk], acc[1]);
      acc[2] = fmaf(q.z, w[kk], acc[2]);
      acc[3] = fmaf(q.w, w[kk], acc[3]);
    }
  }
  float val[4];
  #pragma unroll
  for (int j=0;j<4;j++){
    int bt = bt0 + gdx*4 + j;
    val[j] = acc[j] + 2.f*z[bt*DM + d];
  }
  int w_id = tid>>6;
  #pragma unroll
  for (int j=0;j<4;j++){
    float s = val[j], q = val[j]*val[j];
    #pragma unroll
    for (int off=32; off>=1; off>>=1){ s += __shfl_down(s, off); q += __shfl_down(q, off); }
    if ((tid&63)==0){ psum[w_id][j]=s; psq[w_id][j]=q; }
  }
  __syncthreads();
  float lw = lnw[d], lb = lnb[d];
  #pragma unroll
  for (int j=0;j<4;j++){
    int bt = bt0 + gdx*4 + j;
    float sum = psum[gdx*2][j] + psum[gdx*2+1][j];
    float sq  = psq [gdx*2][j] + psq [gdx*2+1][j];
    float mu  = sum*(1.f/DM);
    float var = sq*(1.f/DM) - mu*mu;
    float inv = rsqrtf(var + 1e-5f);
    out[bt*DM + d] = (val[j]-mu)*inv*lw + lb;
  }
}

extern "C" void kernel_launch(void* const* d_in, const int* in_sizes, int n_in,
                              void* d_out, int out_size, void* d_ws, size_t ws_size,
                              hipStream_t stream){
  const float* zseq = (const float*)d_in[0];
  const float* aux  = (const float*)d_in[1];
  const float* auxW = (const float*)d_in[2];
  const float* auxb = (const float*)d_in[3];
  const float* lnw  = (const float*)d_in[4];
  const float* lnb  = (const float*)d_in[5];
  const float* rmsw = (const float*)d_in[6];
  const float* inW  = (const float*)d_in[7];
  const float* convW= (const float*)d_in[8];
  const float* convb= (const float*)d_in[9];
  const float* xpW  = (const float*)d_in[10];
  const float* dtW  = (const float*)d_in[11];
  const float* dtb  = (const float*)d_in[12];
  const float* Alog = (const float*)d_in[13];
  const float* Dp   = (const float*)d_in[14];
  const float* outW = (const float*)d_in[15];
  float* out = (float*)d_out;
  float* ws = (float*)d_ws;

  float* z   = ws+OFF_Z;    float* zn = ws+OFF_ZN;
  float* xsr = ws+OFF_XSR;  float* zg = ws+OFF_ZG;   float* xs = ws+OFF_XS;
  float* Wc  = ws+OFF_WC;
  float* dl  = ws+OFF_DELTA; float* Bm = ws+OFF_BM;  float* Cm = ws+OFF_CM;
  float* P   = ws+OFF_P;    float* S  = ws+OFF_S;
  float* H0  = ws+OFF_H0;   float* yc = ws+OFF_YC;

  k1_rms   <<<4096,128,0,stream>>>(zseq,aux,auxW,auxb,rmsw,z,zn);
  k2_inproj<<<512,256,0,stream>>>(zn,inW,xsr,zg);
  k3_conv  <<<4096,256,0,stream>>>(xsr,convW,convb,xs);
  k4a_wc   <<<384,256,0,stream>>>(xpW,dtW,Wc);
  k4b_xproj<<<512,384,0,stream>>>(xs,Wc,dtb,dl,Bm,Cm);
  k5a_chunk<<<4096,256,0,stream>>>(dl,xs,Bm,Alog,P,S);
  k5b_h0   <<<256,256,0,stream>>>(P,S,H0);
  k5c_scan <<<4096,256,0,stream>>>(dl,xs,Bm,Cm,zg,Alog,Dp,H0,yc);
  k6_out   <<<512,256,0,stream>>>(yc,outW,z,lnw,lnb,out);
}

// Round 4
// 250.139 us; speedup vs baseline: 1.2407x; 1.2407x over previous
//
#include <hip/hip_runtime.h>
#include <hip/hip_bf16.h>

#define B_SZ 4
#define T_SEQ 1024
#define DM 128
#define ED_ 256
#define NS 64
#define CHUNKS 16
#define CLEN 64

// workspace layout (float elements). Total = 6,389,760 floats = 25.6 MB.
// Aliasing plan:
//   OFF_ZN region is reused for Bm/Cm after K2 is done with zn.
//   OFF_XSR region is reused for delta after K3 is done with xsr.
//   H0 aliases P (K5b reads P[idx],S[idx] BEFORE writing H0[idx], one thread per idx).
//   yraw aliases S (S dead after K5b).
#define OFF_Z      0u         /* 524288  f32  z (residual, read by K6)            */
#define OFF_ZN     524288u    /* 524288  f32  zn; later Bm @ +0, Cm @ +262144     */
#define OFF_XSR    1048576u   /* 1048576 f32  conv input; later delta             */
#define OFF_ZG     2097152u   /* 1048576 f32  gate (read by K6)                   */
#define OFF_XS     3145728u   /* 1048576 f32  conv+silu output (read by K6 too)   */
#define OFF_WC     4194304u   /* 98304   f32  combined x_proj/dt weight (384x256) */
#define OFF_P      4292608u   /* 1048576 f32  chunk decay; later H0 (aliased)     */
#define OFF_S      5341184u   /* 1048576 f32  chunk local scan; later yraw        */

#define OFF_BM     (OFF_ZN)
#define OFF_CM     (OFF_ZN + 262144u)
#define OFF_DELTA  (OFF_XSR)
#define OFF_H0     (OFF_P)
#define OFF_YR     (OFF_S)

__device__ __forceinline__ float sigmoidf_(float x){ return 1.f/(1.f+__expf(-x)); }

// Wave64 sum via DPP (VALU-only, no LDS pipe): row_shr 1/2/4/8 builds per-16-row
// prefix sums (lane 15 of each row = row total), row_bcast15/31 merge rows.
// Total lands in lane 63. Invalid-source lanes contribute old=0.
__device__ __forceinline__ float dpp_reduce_add(float v){
  v += __int_as_float(__builtin_amdgcn_update_dpp(0, __float_as_int(v), 0x111, 0xf, 0xf, false));
  v += __int_as_float(__builtin_amdgcn_update_dpp(0, __float_as_int(v), 0x112, 0xf, 0xf, false));
  v += __int_as_float(__builtin_amdgcn_update_dpp(0, __float_as_int(v), 0x114, 0xf, 0xf, false));
  v += __int_as_float(__builtin_amdgcn_update_dpp(0, __float_as_int(v), 0x118, 0xf, 0xf, false));
  v += __int_as_float(__builtin_amdgcn_update_dpp(0, __float_as_int(v), 0x142, 0xf, 0xf, false));
  v += __int_as_float(__builtin_amdgcn_update_dpp(0, __float_as_int(v), 0x143, 0xf, 0xf, false));
  return v;
}

// K1: z = z_seq + aux @ aux_W.T + aux_b ; zn = RMSNorm(z)*rms_w
__global__ __launch_bounds__(128) void k1_rms(const float* zseq, const float* aux, const float* auxW,
                                              const float* auxb, const float* rmsw, float* z, float* zn){
  int bt = blockIdx.x; int d = threadIdx.x;
  float a0 = aux[bt*3+0], a1 = aux[bt*3+1], a2 = aux[bt*3+2];
  float zv = zseq[bt*DM+d] + a0*auxW[d*3+0] + a1*auxW[d*3+1] + a2*auxW[d*3+2] + auxb[d];
  float s = zv*zv;
  #pragma unroll
  for (int off=32; off>=1; off>>=1) s += __shfl_down(s, off);
  __shared__ float ps[2];
  if ((threadIdx.x&63)==0) ps[threadIdx.x>>6] = s;
  __syncthreads();
  float r = rsqrtf((ps[0]+ps[1])*(1.f/DM) + 1e-5f);
  z[bt*DM+d]  = zv;
  zn[bt*DM+d] = zv*r*rmsw[d];
}

// K2: xz = zn @ in_proj_W.T -> xsr (cols 0..255), zg (cols 256..511). 8 rows/block.
__global__ __launch_bounds__(256) void k2_inproj(const float* zn, const float* W, float* xsr, float* zg){
  __shared__ float at[128][8];
  int bt0 = blockIdx.x*8; int tid = threadIdx.x;
  for (int i=tid; i<1024; i+=256){ int r=i>>7, k=i&127; at[k][r] = zn[(bt0+r)*DM + k]; }
  __syncthreads();
  float acc0[8], acc1[8];
  #pragma unroll
  for (int r=0;r<8;r++){ acc0[r]=0.f; acc1[r]=0.f; }
  int c0 = tid, c1 = tid+256;
  for (int k=0;k<128;k+=4){
    float4 w0v = *(const float4*)(W + c0*128 + k);
    float4 w1v = *(const float4*)(W + c1*128 + k);
    float w0[4] = {w0v.x, w0v.y, w0v.z, w0v.w};
    float w1[4] = {w1v.x, w1v.y, w1v.z, w1v.w};
    #pragma unroll
    for (int kk=0;kk<4;kk++){
      float a[8];
      *(float4*)&a[0] = *(const float4*)&at[k+kk][0];
      *(float4*)&a[4] = *(const float4*)&at[k+kk][4];
      #pragma unroll
      for (int r=0;r<8;r++){ acc0[r] = fmaf(a[r], w0[kk], acc0[r]); acc1[r] = fmaf(a[r], w1[kk], acc1[r]); }
    }
  }
  #pragma unroll
  for (int r=0;r<8;r++){
    int bt = bt0+r;
    xsr[bt*ED_ + c0] = acc0[r];
    zg [bt*ED_ + c0] = acc1[r];
  }
}

// K3: causal depthwise conv (k=4, left pad 3) + bias + SiLU
__global__ __launch_bounds__(256) void k3_conv(const float* xsr, const float* convW, const float* convb, float* xs){
  int bt = blockIdx.x; int e = threadIdx.x; int t = bt & (T_SEQ-1);
  float4 wv = *(const float4*)(convW + e*4);
  float s = convb[e];
  if (t>=3) s += xsr[(bt-3)*ED_+e]*wv.x;
  if (t>=2) s += xsr[(bt-2)*ED_+e]*wv.y;
  if (t>=1) s += xsr[(bt-1)*ED_+e]*wv.z;
  s += xsr[bt*ED_+e]*wv.w;
  xs[bt*ED_+e] = s * sigmoidf_(s);
}

// K4a: combined weight: rows 0..255 = dt_W @ x_proj_W[:8]; rows 256..383 = x_proj_W[8:136]
__global__ __launch_bounds__(256) void k4a_wc(const float* xprojW, const float* dtW, float* Wc){
  int r = blockIdx.x; int k = threadIdx.x;
  float v;
  if (r < 256){
    v = 0.f;
    #pragma unroll
    for (int j=0;j<8;j++) v += dtW[r*8+j] * xprojW[j*256+k];
  } else {
    v = xprojW[(8 + r-256)*256 + k];
  }
  Wc[r*256+k] = v;
}

// K4b: [delta_pre | B | C] = xs @ Wc.T ; delta = softplus(delta_pre + dt_b)
__global__ __launch_bounds__(384) void k4b_xproj(const float* xs, const float* Wc, const float* dtb,
                                                 float* delta, float* Bm, float* Cm){
  __shared__ float at[256][8];
  int bt0 = blockIdx.x*8; int tid = threadIdx.x;
  for (int i=tid;i<2048;i+=384){ int r=i>>8,k=i&255; at[k][r] = xs[(bt0+r)*ED_ + k]; }
  __syncthreads();
  float acc[8];
  #pragma unroll
  for (int r=0;r<8;r++) acc[r]=0.f;
  int c = tid;
  for (int k=0;k<256;k+=4){
    float4 wv = *(const float4*)(Wc + c*256 + k);
    float w[4] = {wv.x, wv.y, wv.z, wv.w};
    #pragma unroll
    for (int kk=0;kk<4;kk++){
      float a[8];
      *(float4*)&a[0] = *(const float4*)&at[k+kk][0];
      *(float4*)&a[4] = *(const float4*)&at[k+kk][4];
      #pragma unroll
      for (int r=0;r<8;r++) acc[r] = fmaf(a[r], w[kk], acc[r]);
    }
  }
  if (c < 256){
    float bc = dtb[c];
    #pragma unroll
    for (int r=0;r<8;r++){
      float x = acc[r] + bc;
      delta[(bt0+r)*ED_ + c] = (x > 20.f) ? x : log1pf(__expf(x));
    }
  } else if (c < 320){
    #pragma unroll
    for (int r=0;r<8;r++) Bm[(bt0+r)*NS + (c-256)] = acc[r];
  } else {
    #pragma unroll
    for (int r=0;r<8;r++) Cm[(bt0+r)*NS + (c-320)] = acc[r];
  }
}

// K5a: per-chunk local scan S (seed 0) and chunk decay P = exp(A * sum(delta)).
// wave g = (b, e, chunk); lane = state n.
__global__ __launch_bounds__(256) void k5a_chunk(const float* delta, const float* xs, const float* Bm,
                                                  const float* Alog, float* P, float* S){
  int g = blockIdx.x*4 + (threadIdx.x>>6);
  int n = threadIdx.x & 63;
  int c = g & 15, e = (g>>4)&255, b = g>>12;
  float A = -__expf(Alog[e*NS+n]);
  int base = b*T_SEQ + c*CLEN;
  const float* pd = delta + base*ED_ + e;
  const float* px = xs    + base*ED_ + e;
  const float* pb = Bm    + base*NS  + n;
  float s = 0.f, sd = 0.f;
  #pragma unroll 4
  for (int tt=0; tt<CLEN; ++tt){
    float dlt = pd[tt*ED_];
    float x   = px[tt*ED_];
    float bm  = pb[tt*NS];
    float a = __expf(dlt*A);
    s = fmaf(a, s, dlt*x*bm);
    sd += dlt;
  }
  P[g*NS+n] = __expf(sd*A);
  S[g*NS+n] = s;
}

// K5b: chunk-prefix: H0[c] = scan of (P,S) over chunks, one thread per (b,e,n).
// NOTE: H0 aliases P — each element is read (p,s) BEFORE H0[idx] is written,
// and each idx is owned by exactly one thread. Do not add __restrict__ here.
__global__ __launch_bounds__(256) void k5b_h0(const float* P, const float* S, float* H0){
  int t = blockIdx.x*256 + threadIdx.x;
  int n = t & 63, e = (t>>6)&255, b = t>>14;
  int gb = (b*256+e)*16;
  float h = 0.f;
  for (int c=0;c<16;c++){
    int idx = (gb+c)*64 + n;
    float p = P[idx];
    float s = S[idx];
    H0[idx] = h;
    h = fmaf(p, h, s);
  }
}

// K5c: final scan seeded with H0; stores RAW dot p[t] = sum_n h*C (lane 63 via DPP).
// Gate (+D*x, *silu(zg)) is applied in K6's staging. yraw aliases S (dead).
__global__ __launch_bounds__(256) void k5c_scan(const float* delta, const float* xs, const float* Bm,
                                                 const float* Cm, const float* Alog,
                                                 const float* H0, float* yraw){
  int g = blockIdx.x*4 + (threadIdx.x>>6);
  int n = threadIdx.x & 63;
  int c = g & 15, e = (g>>4)&255, b = g>>12;
  float A = -__expf(Alog[e*NS+n]);
  float h = H0[g*NS+n];
  int base = b*T_SEQ + c*CLEN;
  const float* pd = delta + base*ED_ + e;
  const float* px = xs    + base*ED_ + e;
  const float* pb = Bm    + base*NS  + n;
  const float* pc = Cm    + base*NS  + n;
  float*       py = yraw  + base*ED_ + e;
  #pragma unroll 4
  for (int tt=0; tt<CLEN; ++tt){
    float dlt = pd[tt*ED_];
    float x   = px[tt*ED_];
    float bm  = pb[tt*NS];
    float cm  = pc[tt*NS];
    float a = __expf(dlt*A);
    h = fmaf(a, h, dlt*x*bm);
    float p = dpp_reduce_add(h*cm);
    if (n==63) py[tt*ED_] = p;
  }
}

// K6: y = (yraw + D*xs)*silu(zg);  out = LayerNorm(y @ out_proj_W.T + 2*z)*ln_w + ln_b
__global__ __launch_bounds__(256) void k6_out(const float* yraw, const float* xs, const float* zg,
                                               const float* Dp, const float* W, const float* z,
                                               const float* lnw, const float* lnb, float* out){
  __shared__ float yt[256][8];
  __shared__ float psum[4][4], psq[4][4];
  int bt0 = blockIdx.x*8; int tid = threadIdx.x;
  int d = tid & 127, gdx = tid>>7;
  for (int i=tid;i<2048;i+=256){
    int r=i>>8,k=i&255; int bt=bt0+r;
    float zgv = zg[bt*ED_ + k];
    float yv  = yraw[bt*ED_ + k] + Dp[k]*xs[bt*ED_ + k];
    yt[k][r] = yv * zgv * sigmoidf_(zgv);
  }
  __syncthreads();
  float acc[4] = {0.f,0.f,0.f,0.f};
  for (int k=0;k<256;k+=4){
    float4 wv = *(const float4*)(W + d*256 + k);
    float w[4] = {wv.x, wv.y, wv.z, wv.w};
    #pragma unroll
    for (int kk=0;kk<4;kk++){
      float4 q = *(const float4*)&yt[k+kk][gdx*4];
      acc[0] = fmaf(q.x, w[kk], acc[0]);
      acc[1] = fmaf(q.y, w[kk], acc[1]);
      acc[2] = fmaf(q.z, w[kk], acc[2]);
      acc[3] = fmaf(q.w, w[kk], acc[3]);
    }
  }
  float val[4];
  #pragma unroll
  for (int j=0;j<4;j++){
    int bt = bt0 + gdx*4 + j;
    val[j] = acc[j] + 2.f*z[bt*DM + d];
  }
  int w_id = tid>>6;
  #pragma unroll
  for (int j=0;j<4;j++){
    float s = val[j], q = val[j]*val[j];
    #pragma unroll
    for (int off=32; off>=1; off>>=1){ s += __shfl_down(s, off); q += __shfl_down(q, off); }
    if ((tid&63)==0){ psum[w_id][j]=s; psq[w_id][j]=q; }
  }
  __syncthreads();
  float lw = lnw[d], lb = lnb[d];
  #pragma unroll
  for (int j=0;j<4;j++){
    int bt = bt0 + gdx*4 + j;
    float sum = psum[gdx*2][j] + psum[gdx*2+1][j];
    float sq  = psq [gdx*2][j] + psq [gdx*2+1][j];
    float mu  = sum*(1.f/DM);
    float var = sq*(1.f/DM) - mu*mu;
    float inv = rsqrtf(var + 1e-5f);
    out[bt*DM + d] = (val[j]-mu)*inv*lw + lb;
  }
}

extern "C" void kernel_launch(void* const* d_in, const int* in_sizes, int n_in,
                              void* d_out, int out_size, void* d_ws, size_t ws_size,
                              hipStream_t stream){
  const float* zseq = (const float*)d_in[0];
  const float* aux  = (const float*)d_in[1];
  const float* auxW = (const float*)d_in[2];
  const float* auxb = (const float*)d_in[3];
  const float* lnw  = (const float*)d_in[4];
  const float* lnb  = (const float*)d_in[5];
  const float* rmsw = (const float*)d_in[6];
  const float* inW  = (const float*)d_in[7];
  const float* convW= (const float*)d_in[8];
  const float* convb= (const float*)d_in[9];
  const float* xpW  = (const float*)d_in[10];
  const float* dtW  = (const float*)d_in[11];
  const float* dtb  = (const float*)d_in[12];
  const float* Alog = (const float*)d_in[13];
  const float* Dp   = (const float*)d_in[14];
  const float* outW = (const float*)d_in[15];
  float* out = (float*)d_out;
  float* ws = (float*)d_ws;

  float* z   = ws+OFF_Z;    float* zn = ws+OFF_ZN;
  float* xsr = ws+OFF_XSR;  float* zg = ws+OFF_ZG;   float* xs = ws+OFF_XS;
  float* Wc  = ws+OFF_WC;
  float* dl  = ws+OFF_DELTA; float* Bm = ws+OFF_BM;  float* Cm = ws+OFF_CM;
  float* P   = ws+OFF_P;    float* S  = ws+OFF_S;
  float* H0  = ws+OFF_H0;   float* yr = ws+OFF_YR;

  k1_rms   <<<4096,128,0,stream>>>(zseq,aux,auxW,auxb,rmsw,z,zn);
  k2_inproj<<<512,256,0,stream>>>(zn,inW,xsr,zg);
  k3_conv  <<<4096,256,0,stream>>>(xsr,convW,convb,xs);
  k4a_wc   <<<384,256,0,stream>>>(xpW,dtW,Wc);
  k4b_xproj<<<512,384,0,stream>>>(xs,Wc,dtb,dl,Bm,Cm);
  k5a_chunk<<<4096,256,0,stream>>>(dl,xs,Bm,Alog,P,S);
  k5b_h0   <<<256,256,0,stream>>>(P,S,H0);
  k5c_scan <<<4096,256,0,stream>>>(dl,xs,Bm,Cm,Alog,H0,yr);
  k6_out   <<<512,256,0,stream>>>(yr,xs,zg,Dp,outW,z,lnw,lnb,out);
}